// Round 6
// baseline (919.600 us; speedup 1.0000x reference)
//
#include <hip/hip_runtime.h>
#include <hip/hip_bf16.h>

typedef __attribute__((ext_vector_type(8))) short short8;
typedef __attribute__((ext_vector_type(4))) float f32x4;

__device__ __forceinline__ unsigned short fbf(float f) {
  union { float f; unsigned u; } v; v.f = f;
  unsigned r = v.u + 0x7fffu + ((v.u >> 16) & 1u);   // RNE
  return (unsigned short)(r >> 16);
}
__device__ __forceinline__ unsigned pk2(float a, float b) {
  return (unsigned)fbf(a) | ((unsigned)fbf(b) << 16);
}
__device__ __forceinline__ float ubf(unsigned hi) {   // bf16 bits (low16) -> float
  union { unsigned u; float f; } v; v.u = hi << 16; return v.f;
}
__device__ __forceinline__ float dot4(float4 a, float4 b) {
  return fmaf(a.x, b.x, fmaf(a.y, b.y, fmaf(a.z, b.z, a.w * b.w)));
}

// ---------------- CSR build ----------------
__global__ void k_count(const int* __restrict__ dst, int E, int* __restrict__ deg) {
  for (int i = blockIdx.x * blockDim.x + threadIdx.x; i < E; i += gridDim.x * blockDim.x)
    atomicAdd(&deg[dst[i]], 1);
}

__global__ void k_scan1(const int* __restrict__ deg, int N, int* __restrict__ part,
                        int* __restrict__ bsum) {
  __shared__ int tmp[1024];
  int tid = threadIdx.x;
  int i = blockIdx.x * 1024 + tid;
  int v = (i < N) ? deg[i] : 0;
  tmp[tid] = v;
  __syncthreads();
  for (int ofs = 1; ofs < 1024; ofs <<= 1) {
    int t = (tid >= ofs) ? tmp[tid - ofs] : 0;
    __syncthreads();
    tmp[tid] += t;
    __syncthreads();
  }
  if (i < N) part[i] = tmp[tid] - v;
  if (tid == 1023) bsum[blockIdx.x] = tmp[tid];
}

__global__ void k_scan2(int* __restrict__ part, const int* __restrict__ bsum, int N,
                        int* __restrict__ cursor) {
  __shared__ int sbase;
  if (threadIdx.x == 0) {
    int b = 0;
    for (int j = 0; j < (int)blockIdx.x; j++) b += bsum[j];
    sbase = b;
  }
  __syncthreads();
  int i = blockIdx.x * 1024 + threadIdx.x;
  if (i < N) {
    int o = part[i] + sbase;
    part[i] = o;
    cursor[i] = o;
  }
}

__global__ void k_fill(const int* __restrict__ src, const int* __restrict__ dst, int E,
                       int* __restrict__ cursor, int2* __restrict__ csr2) {
  for (int i = blockIdx.x * blockDim.x + threadIdx.x; i < E; i += gridDim.x * blockDim.x) {
    int d = dst[i];
    int slot = atomicAdd(&cursor[d], 1);
    csr2[slot] = make_int2(src[i], i);
  }
}

// ---------------- A_s / A_d tables + x -> bf16 (fused, single x read) ----------------
__launch_bounds__(256)
__global__ void k_prep(const float* __restrict__ x, const float* __restrict__ W_att,
                       float4* __restrict__ A_s, float4* __restrict__ A_d,
                       unsigned* __restrict__ xb32, int N) {
  __shared__ float4 s_wa[160];                 // 4 heads x 40 float4 (row len 160)
  if (threadIdx.x < 160) s_wa[threadIdx.x] = ((const float4*)W_att)[threadIdx.x];
  __syncthreads();
  for (int v = blockIdx.x * blockDim.x + threadIdx.x; v < N; v += gridDim.x * blockDim.x) {
    const float4* xp = (const float4*)&x[v * 64];
    float4 xq[16];
    #pragma unroll
    for (int k = 0; k < 16; k++) xq[k] = xp[k];
    float as[4] = {}, ad[4] = {};
    #pragma unroll
    for (int h = 0; h < 4; h++) {
      #pragma unroll
      for (int k = 0; k < 16; k++) {
        as[h] += dot4(s_wa[h * 40 + k], xq[k]);
        ad[h] += dot4(s_wa[h * 40 + 16 + k], xq[k]);
      }
    }
    A_s[v] = make_float4(as[0], as[1], as[2], as[3]);
    A_d[v] = make_float4(ad[0], ad[1], ad[2], ad[3]);
    #pragma unroll
    for (int k = 0; k < 16; k++) {
      xb32[v * 32 + 2 * k]     = pk2(xq[k].x, xq[k].y);
      xb32[v * 32 + 2 * k + 1] = pk2(xq[k].z, xq[k].w);
    }
  }
}

// ---------------- fused att + weighted aggregation (wave per node, pipelined) --------
struct GBuf {
  unsigned short xv[8];
  float ev[8];
  float4 ef, asv;
};

__launch_bounds__(256, 4)
__global__ void k_agg(const unsigned short* __restrict__ xb, const float* __restrict__ ea,
                      const float4* __restrict__ A_s, const float4* __restrict__ A_d,
                      const int2* __restrict__ csr2, const int* __restrict__ offsets,
                      const int* __restrict__ deg, const float* __restrict__ W_att,
                      unsigned short* __restrict__ agg, float* __restrict__ denom,
                      int N, int Ec) {
  __shared__ int2 s_ids[4][32];       // wave-private quad of edge ids
  __shared__ float4 s_att[4][8];      // wave-private att broadcast
  const int lane = threadIdx.x & 63;
  const int wvb = threadIdx.x >> 6;
  const int wv = (blockIdx.x * blockDim.x + threadIdx.x) >> 6;
  const int nw = (gridDim.x * blockDim.x) >> 6;
  const int l32 = lane & 31;
  const bool hi = (lane & 32) != 0;
  const int pj = lane >> 3;           // logit edge (0..7)
  const int jc = lane & 7;            // float4 chunk of ea row
  const float jc0f = (jc == 0) ? 1.f : 0.f;

  const float4 wea0 = *(const float4*)&W_att[0 * 160 + 128 + jc * 4];
  const float4 wea1 = *(const float4*)&W_att[1 * 160 + 128 + jc * 4];
  const float4 wea2 = *(const float4*)&W_att[2 * 160 + 128 + jc * 4];
  const float4 wea3 = *(const float4*)&W_att[3 * 160 + 128 + jc * 4];

#define ISSUE_G(B, g) do {                                                  \
    const int qo8_ = ((g) & 3) * 8;                                         \
    _Pragma("unroll")                                                       \
    for (int p = 0; p < 8; p++) {                                           \
      int2 idp = s_ids[wvb][qo8_ + p];                                      \
      int sps = __builtin_amdgcn_readfirstlane(idp.x);                      \
      int eps = __builtin_amdgcn_readfirstlane(idp.y);                      \
      B.xv[p] = xb[(size_t)sps * 64 + lane];                                \
      B.ev[p] = ea[(size_t)eps * 32 + l32];                                 \
    }                                                                       \
    int2 idl_ = s_ids[wvb][qo8_ + pj];                                      \
    B.ef = *(const float4*)&ea[(size_t)idl_.y * 32 + jc * 4];               \
    B.asv = A_s[idl_.x];                                                    \
  } while (0)

#define COMPUTE_G(B, g) do {                                                \
    float lp0 = dot4(wea0, B.ef), lp1 = dot4(wea1, B.ef);                   \
    float lp2 = dot4(wea2, B.ef), lp3 = dot4(wea3, B.ef);                   \
    _Pragma("unroll")                                                       \
    for (int m = 1; m <= 4; m <<= 1) {                                      \
      lp0 += __shfl_xor(lp0, m, 64); lp1 += __shfl_xor(lp1, m, 64);         \
      lp2 += __shfl_xor(lp2, m, 64); lp3 += __shfl_xor(lp3, m, 64);         \
    }                                                                       \
    const float msk_ = ((g) * 8 + pj < dg) ? 1.f : 0.f;                     \
    float4 av_; float lg_;                                                  \
    lg_ = lp0 + B.asv.x + adv.x; lg_ = (lg_ > 0.f) ? lg_ : 0.2f * lg_;      \
    av_.x = msk_ * __expf(lg_);                                             \
    lg_ = lp1 + B.asv.y + adv.y; lg_ = (lg_ > 0.f) ? lg_ : 0.2f * lg_;      \
    av_.y = msk_ * __expf(lg_);                                             \
    lg_ = lp2 + B.asv.z + adv.z; lg_ = (lg_ > 0.f) ? lg_ : 0.2f * lg_;      \
    av_.z = msk_ * __expf(lg_);                                             \
    lg_ = lp3 + B.asv.w + adv.w; lg_ = (lg_ > 0.f) ? lg_ : 0.2f * lg_;      \
    av_.w = msk_ * __expf(lg_);                                             \
    if (jc == 0) s_att[wvb][pj] = av_;                                      \
    ssa.x = fmaf(av_.x, jc0f, ssa.x); ssa.y = fmaf(av_.y, jc0f, ssa.y);     \
    ssa.z = fmaf(av_.z, jc0f, ssa.z); ssa.w = fmaf(av_.w, jc0f, ssa.w);     \
    _Pragma("unroll")                                                       \
    for (int p = 0; p < 8; p++) {                                           \
      float4 ap = s_att[wvb][p];                                            \
      float xf = ubf((unsigned)B.xv[p]);                                    \
      ax0 = fmaf(ap.x, xf, ax0); ax1 = fmaf(ap.y, xf, ax1);                 \
      ax2 = fmaf(ap.z, xf, ax2); ax3 = fmaf(ap.w, xf, ax3);                 \
      ae0 = fmaf(hi ? ap.z : ap.x, B.ev[p], ae0);                           \
      ae1 = fmaf(hi ? ap.w : ap.y, B.ev[p], ae1);                           \
    }                                                                       \
  } while (0)

  int v = wv;
  int start = 0, dg = 0;
  float4 adv = make_float4(0.f, 0.f, 0.f, 0.f);
  int2 qcur = make_int2(0, 0);
  if (v < N) {                               // first-node prologue (once)
    start = offsets[v];
    dg = deg[v];
    adv = A_d[v];
    int lim = start + ((dg > 0) ? min(l32, dg - 1) : 0);
    qcur = csr2[min(lim, Ec - 1)];
  }

  while (v < N) {
    const int v_next = v + nw;
    int start_n = 0, dg_n = 0;
    float4 adv_n = make_float4(0.f, 0.f, 0.f, 0.f);
    if (v_next < N) {                        // issue next-node meta early
      start_n = offsets[v_next];
      dg_n = deg[v_next];
      adv_n = A_d[v_next];
    }

    float ax0 = 0, ax1 = 0, ax2 = 0, ax3 = 0, ae0 = 0, ae1 = 0;
    float4 ssa = make_float4(0.f, 0.f, 0.f, 0.f);
    int2 qn = make_int2(0, 0);
    bool qn_done = false;

    if (dg > 0) {
      if (lane < 32) s_ids[wvb][l32] = qcur;
      const int ng = (dg + 7) >> 3;
      GBuf A, B;
      ISSUE_G(A, 0);
      int g = 0;
      while (true) {
        if (g + 1 < ng) {
          if (((g + 1) & 3) == 0) {          // rare quad refill (deg > 32)
            int2 q = csr2[start + min((g + 1) * 8 + l32, dg - 1)];
            if (lane < 32) s_ids[wvb][l32] = q;
          }
          ISSUE_G(B, g + 1);
        }
        COMPUTE_G(A, g);
        if (g == 0 && v_next < N) {          // next node's quad0 (start_n arrived)
          int lim = start_n + ((dg_n > 0) ? min(l32, dg_n - 1) : 0);
          qn = csr2[min(lim, Ec - 1)];
          qn_done = true;
        }
        if (++g >= ng) break;
        if (g + 1 < ng) {
          if (((g + 1) & 3) == 0) {
            int2 q = csr2[start + min((g + 1) * 8 + l32, dg - 1)];
            if (lane < 32) s_ids[wvb][l32] = q;
          }
          ISSUE_G(A, g + 1);
        }
        COMPUTE_G(B, g);
        if (++g >= ng) break;
      }
    }
    if (!qn_done && v_next < N) {
      int lim = start_n + ((dg_n > 0) ? min(l32, dg_n - 1) : 0);
      qn = csr2[min(lim, Ec - 1)];
    }

    // per-node epilogue: reduce denom, write agg (bf16) + denom
    #pragma unroll
    for (int m = 1; m <= 32; m <<= 1) {
      ssa.x += __shfl_xor(ssa.x, m, 64);
      ssa.y += __shfl_xor(ssa.y, m, 64);
      ssa.z += __shfl_xor(ssa.z, m, 64);
      ssa.w += __shfl_xor(ssa.w, m, 64);
    }
    const int base = v * 384;
    agg[base + lane]       = fbf(ax0);
    agg[base + 96 + lane]  = fbf(ax1);
    agg[base + 192 + lane] = fbf(ax2);
    agg[base + 288 + lane] = fbf(ax3);
    const int hA = hi ? 2 : 0;
    agg[base + hA * 96 + 64 + l32]       = fbf(ae0);
    agg[base + (hA + 1) * 96 + 64 + l32] = fbf(ae1);
    if (lane == 0) ((float4*)denom)[v] = ssa;

    v = v_next; start = start_n; dg = dg_n; adv = adv_n; qcur = qn;
  }
#undef ISSUE_G
#undef COMPUTE_G
}

// ---------------- out = blockdiag(W_msg) * agg, /denom, +bias, LN ----------------
__launch_bounds__(128)
__global__ void k_out(const unsigned short* __restrict__ agg, const float* __restrict__ W_msg,
                      const float* __restrict__ denom, const float* __restrict__ bias,
                      const float* __restrict__ gamma, const float* __restrict__ beta,
                      float* __restrict__ out, int N, int T) {
  __shared__ float s_den[64];
  __shared__ float s_sum[2][16], s_sq[2][16];
  const int f = threadIdx.x;
  const int w = f >> 6;            // wave: heads 2w, 2w+1 -> cols 64w..64w+63
  const int l = f & 63;
  const int c16 = l & 15;
  const int rg = l >> 4;

  short8 wb[2][2][3];
  float biasv[2][2], gv[2][2], bv[2][2];
  #pragma unroll
  for (int hh = 0; hh < 2; hh++) {
    const int head = 2 * w + hh;
    #pragma unroll
    for (int ct = 0; ct < 2; ct++) {
      const int q = head * 32 + ct * 16 + c16;
      biasv[hh][ct] = bias[q]; gv[hh][ct] = gamma[q]; bv[hh][ct] = beta[q];
      #pragma unroll
      for (int kk = 0; kk < 3; kk++) {
        const float* p = &W_msg[q * 96 + kk * 32 + rg * 8];
        short8 s;
        #pragma unroll
        for (int i = 0; i < 8; i++) s[i] = (short)fbf(p[i]);
        wb[hh][ct][kk] = s;
      }
    }
  }

  for (int t = blockIdx.x; t < T; t += gridDim.x) {
    const int n0 = t * 16;
    if (f < 64) s_den[f] = denom[min(n0 + (f >> 2), N - 1) * 4 + (f & 3)];
    __syncthreads();

    f32x4 c[2][2] = {{{0.f,0.f,0.f,0.f},{0.f,0.f,0.f,0.f}},
                     {{0.f,0.f,0.f,0.f},{0.f,0.f,0.f,0.f}}};
    const int nA = min(n0 + c16, N - 1);
    #pragma unroll
    for (int hh = 0; hh < 2; hh++) {
      const int head = 2 * w + hh;
      #pragma unroll
      for (int kk = 0; kk < 3; kk++) {
        short8 a = *(const short8*)&agg[nA * 384 + head * 96 + kk * 32 + rg * 8];
        c[hh][0] = __builtin_amdgcn_mfma_f32_16x16x32_bf16(a, wb[hh][0][kk], c[hh][0], 0, 0, 0);
        c[hh][1] = __builtin_amdgcn_mfma_f32_16x16x32_bf16(a, wb[hh][1][kk], c[hh][1], 0, 0, 0);
      }
    }

    float val[2][2][4];
    #pragma unroll
    for (int hh = 0; hh < 2; hh++)
      #pragma unroll
      for (int ct = 0; ct < 2; ct++)
        #pragma unroll
        for (int r = 0; r < 4; r++) {
          const float d = s_den[(rg * 4 + r) * 4 + (2 * w + hh)] + 1e-9f;
          val[hh][ct][r] = c[hh][ct][r] / d + biasv[hh][ct];
        }

    float sr[4], qr[4];
    #pragma unroll
    for (int r = 0; r < 4; r++) {
      float s = 0.f, q2 = 0.f;
      #pragma unroll
      for (int hh = 0; hh < 2; hh++)
        #pragma unroll
        for (int ct = 0; ct < 2; ct++) { s += val[hh][ct][r]; q2 = fmaf(val[hh][ct][r], val[hh][ct][r], q2); }
      #pragma unroll
      for (int m = 1; m <= 8; m <<= 1) { s += __shfl_xor(s, m, 64); q2 += __shfl_xor(q2, m, 64); }
      sr[r] = s; qr[r] = q2;
    }
    if (c16 == 0) {
      #pragma unroll
      for (int r = 0; r < 4; r++) { s_sum[w][rg * 4 + r] = sr[r]; s_sq[w][rg * 4 + r] = qr[r]; }
    }
    __syncthreads();

    float mean[4], rstd[4];
    #pragma unroll
    for (int r = 0; r < 4; r++) {
      const int ni = rg * 4 + r;
      mean[r] = (s_sum[0][ni] + s_sum[1][ni]) * (1.f / 128.f);
      const float m2 = (s_sq[0][ni] + s_sq[1][ni]) * (1.f / 128.f);
      rstd[r] = rsqrtf(m2 - mean[r] * mean[r] + 1e-5f);
    }
    #pragma unroll
    for (int hh = 0; hh < 2; hh++)
      #pragma unroll
      for (int ct = 0; ct < 2; ct++)
        #pragma unroll
        for (int r = 0; r < 4; r++) {
          const int n = n0 + rg * 4 + r;
          if (n < N)
            out[n * 128 + (2 * w + hh) * 32 + ct * 16 + c16] =
                (val[hh][ct][r] - mean[r]) * rstd[r] * gv[hh][ct] + bv[hh][ct];
        }
    __syncthreads();
  }
}

extern "C" void kernel_launch(void* const* d_in, const int* in_sizes, int n_in,
                              void* d_out, int out_size, void* d_ws, size_t ws_size,
                              hipStream_t stream) {
  const float* x     = (const float*)d_in[0];
  const int*   ei    = (const int*)d_in[1];
  const float* ea    = (const float*)d_in[2];
  const float* W_msg = (const float*)d_in[3];
  const float* W_att = (const float*)d_in[4];
  const float* bias  = (const float*)d_in[5];
  const float* gamma = (const float*)d_in[6];
  const float* beta  = (const float*)d_in[7];
  float* out = (float*)d_out;

  const int N = in_sizes[0] / 64;
  const int E = in_sizes[1] / 2;
  const int* esrc = ei;
  const int* edst = ei + E;

  char* p = (char*)d_ws;
  int* deg      = (int*)p;            p += (size_t)N * 4;
  int* offsets  = (int*)p;            p += (size_t)N * 4;
  int* cursor   = (int*)p;            p += (size_t)N * 4;
  int* bsum     = (int*)p;            p += 2048 * 4;
  int2* csr2    = (int2*)p;           p += (size_t)E * 8;
  float4* A_s   = (float4*)p;         p += (size_t)N * 16;
  float4* A_d   = (float4*)p;         p += (size_t)N * 16;
  unsigned short* xb = (unsigned short*)p; p += (size_t)N * 64 * 2;
  unsigned short* agg = (unsigned short*)p; p += (size_t)N * 384 * 2;
  float* denom  = (float*)p;

  hipMemsetAsync(deg, 0, (size_t)N * sizeof(int), stream);
  const int SB = (N + 1023) / 1024;
  const int T = (N + 15) / 16;

  k_count<<<2048, 256, 0, stream>>>(edst, E, deg);
  k_scan1<<<SB, 1024, 0, stream>>>(deg, N, offsets, bsum);
  k_scan2<<<SB, 1024, 0, stream>>>(offsets, bsum, N, cursor);
  k_fill<<<2048, 256, 0, stream>>>(esrc, edst, E, cursor, csr2);
  k_prep<<<(N + 255) / 256, 256, 0, stream>>>(x, W_att, A_s, A_d, (unsigned*)xb, N);
  k_agg<<<2048, 256, 0, stream>>>(xb, ea, A_s, A_d, csr2, offsets, deg, W_att,
                                  agg, denom, N, E);
  k_out<<<2048, 128, 0, stream>>>(agg, W_msg, denom, bias, gamma, beta, out, N, T);
}

// Round 7
// 418.651 us; speedup vs baseline: 2.1966x; 2.1966x over previous
//
#include <hip/hip_runtime.h>
#include <hip/hip_bf16.h>

typedef __attribute__((ext_vector_type(8))) short short8;
typedef __attribute__((ext_vector_type(4))) float f32x4;

__device__ __forceinline__ unsigned short fbf(float f) {
  union { float f; unsigned u; } v; v.f = f;
  unsigned r = v.u + 0x7fffu + ((v.u >> 16) & 1u);   // RNE
  return (unsigned short)(r >> 16);
}
__device__ __forceinline__ unsigned pk2(float a, float b) {
  return (unsigned)fbf(a) | ((unsigned)fbf(b) << 16);
}
__device__ __forceinline__ float ubf(unsigned hi) {   // bf16 bits (low16) -> float
  union { unsigned u; float f; } v; v.u = hi << 16; return v.f;
}
__device__ __forceinline__ float dot4(float4 a, float4 b) {
  return fmaf(a.x, b.x, fmaf(a.y, b.y, fmaf(a.z, b.z, a.w * b.w)));
}

// ---------------- CSR build ----------------
__global__ void k_count(const int* __restrict__ dst, int E, int* __restrict__ deg) {
  for (int i = blockIdx.x * blockDim.x + threadIdx.x; i < E; i += gridDim.x * blockDim.x)
    atomicAdd(&deg[dst[i]], 1);
}

__global__ void k_scan1(const int* __restrict__ deg, int N, int* __restrict__ part,
                        int* __restrict__ bsum) {
  __shared__ int tmp[1024];
  int tid = threadIdx.x;
  int i = blockIdx.x * 1024 + tid;
  int v = (i < N) ? deg[i] : 0;
  tmp[tid] = v;
  __syncthreads();
  for (int ofs = 1; ofs < 1024; ofs <<= 1) {
    int t = (tid >= ofs) ? tmp[tid - ofs] : 0;
    __syncthreads();
    tmp[tid] += t;
    __syncthreads();
  }
  if (i < N) part[i] = tmp[tid] - v;
  if (tid == 1023) bsum[blockIdx.x] = tmp[tid];
}

__global__ void k_scan2(int* __restrict__ part, const int* __restrict__ bsum, int N,
                        int* __restrict__ cursor) {
  __shared__ int sbase;
  if (threadIdx.x == 0) {
    int b = 0;
    for (int j = 0; j < (int)blockIdx.x; j++) b += bsum[j];
    sbase = b;
  }
  __syncthreads();
  int i = blockIdx.x * 1024 + threadIdx.x;
  if (i < N) {
    int o = part[i] + sbase;
    part[i] = o;
    cursor[i] = o;
  }
}

__global__ void k_fill(const int* __restrict__ src, const int* __restrict__ dst, int E,
                       int* __restrict__ cursor, int2* __restrict__ csr2) {
  for (int i = blockIdx.x * blockDim.x + threadIdx.x; i < E; i += gridDim.x * blockDim.x) {
    int d = dst[i];
    int slot = atomicAdd(&cursor[d], 1);
    csr2[slot] = make_int2(src[i], i);
  }
}

// ---------------- A_s / A_d tables + x -> bf16 (fused, single x read) ----------------
__launch_bounds__(256)
__global__ void k_prep(const float* __restrict__ x, const float* __restrict__ W_att,
                       float4* __restrict__ A_s, float4* __restrict__ A_d,
                       unsigned* __restrict__ xb32, int N) {
  __shared__ float4 s_wa[160];                 // 4 heads x 40 float4 (row len 160)
  if (threadIdx.x < 160) s_wa[threadIdx.x] = ((const float4*)W_att)[threadIdx.x];
  __syncthreads();
  for (int v = blockIdx.x * blockDim.x + threadIdx.x; v < N; v += gridDim.x * blockDim.x) {
    const float4* xp = (const float4*)&x[v * 64];
    float4 xq[16];
    #pragma unroll
    for (int k = 0; k < 16; k++) xq[k] = xp[k];
    float as[4] = {}, ad[4] = {};
    #pragma unroll
    for (int h = 0; h < 4; h++) {
      #pragma unroll
      for (int k = 0; k < 16; k++) {
        as[h] += dot4(s_wa[h * 40 + k], xq[k]);
        ad[h] += dot4(s_wa[h * 40 + 16 + k], xq[k]);
      }
    }
    A_s[v] = make_float4(as[0], as[1], as[2], as[3]);
    A_d[v] = make_float4(ad[0], ad[1], ad[2], ad[3]);
    #pragma unroll
    for (int k = 0; k < 16; k++) {
      xb32[v * 32 + 2 * k]     = pk2(xq[k].x, xq[k].y);
      xb32[v * 32 + 2 * k + 1] = pk2(xq[k].z, xq[k].w);
    }
  }
}

// ------- fused att + weighted aggregation (wave per node, 2-stage pipeline) -------
__launch_bounds__(256)
__global__ void k_agg(const unsigned short* __restrict__ xb, const float* __restrict__ ea,
                      const float4* __restrict__ A_s, const float4* __restrict__ A_d,
                      const int2* __restrict__ csr2, const int* __restrict__ offsets,
                      const int* __restrict__ deg, const float* __restrict__ W_att,
                      unsigned short* __restrict__ agg, float* __restrict__ denom, int N) {
  __shared__ int2 s_ids[4][32];       // wave-private quad (32 edge ids)
  __shared__ float4 s_att[4][8];      // wave-private att broadcast
  const int lane = threadIdx.x & 63;
  const int wvb = threadIdx.x >> 6;
  const int wv = (blockIdx.x * blockDim.x + threadIdx.x) >> 6;
  const int nw = (gridDim.x * blockDim.x) >> 6;
  const int l32 = lane & 31;
  const bool hi = (lane & 32) != 0;
  const int pj = lane >> 3;           // logit edge (0..7)
  const int jc = lane & 7;            // float4 chunk of ea row
  const float jc0f = (jc == 0) ? 1.f : 0.f;

  const float4 wea0 = *(const float4*)&W_att[0 * 160 + 128 + jc * 4];
  const float4 wea1 = *(const float4*)&W_att[1 * 160 + 128 + jc * 4];
  const float4 wea2 = *(const float4*)&W_att[2 * 160 + 128 + jc * 4];
  const float4 wea3 = *(const float4*)&W_att[3 * 160 + 128 + jc * 4];

  // flat double-buffer registers (statically indexed only)
  unsigned short axv[8], bxv[8];
  float aev[8], bev[8];
  float4 aef, aasv, bef, basv;

#define REFILL(g) do {                                                      \
    if (((g) & 3) == 0) {                                                   \
      int2 q_ = csr2[start + min((g) * 8 + l32, dg - 1)];                   \
      if (lane < 32) s_ids[wvb][l32] = q_;                                  \
    }                                                                       \
  } while (0)

#define ISSUE_G(X, E4, AS, g) do {                                          \
    const int qo_ = ((g) & 3) * 8;                                          \
    _Pragma("unroll")                                                       \
    for (int p = 0; p < 8; p++) {                                           \
      int2 t_ = s_ids[wvb][qo_ + p];                                        \
      X[p] = xb[(size_t)t_.x * 64 + lane];                                  \
      E4[p] = ea[(size_t)t_.y * 32 + l32];                                  \
    }                                                                       \
    int2 idl_ = s_ids[wvb][qo_ + pj];                                       \
    AS##ef = *(const float4*)&ea[(size_t)idl_.y * 32 + jc * 4];             \
    AS##asv = A_s[idl_.x];                                                  \
  } while (0)

#define COMPUTE_G(X, E4, AS, g) do {                                        \
    float lp0 = dot4(wea0, AS##ef), lp1 = dot4(wea1, AS##ef);               \
    float lp2 = dot4(wea2, AS##ef), lp3 = dot4(wea3, AS##ef);               \
    _Pragma("unroll")                                                       \
    for (int m = 1; m <= 4; m <<= 1) {                                      \
      lp0 += __shfl_xor(lp0, m, 64); lp1 += __shfl_xor(lp1, m, 64);         \
      lp2 += __shfl_xor(lp2, m, 64); lp3 += __shfl_xor(lp3, m, 64);         \
    }                                                                       \
    const float msk_ = ((g) * 8 + pj < dg) ? 1.f : 0.f;                     \
    float4 av_; float lg_;                                                  \
    lg_ = lp0 + AS##asv.x + adv.x; lg_ = (lg_ > 0.f) ? lg_ : 0.2f * lg_;    \
    av_.x = msk_ * __expf(lg_);                                             \
    lg_ = lp1 + AS##asv.y + adv.y; lg_ = (lg_ > 0.f) ? lg_ : 0.2f * lg_;    \
    av_.y = msk_ * __expf(lg_);                                             \
    lg_ = lp2 + AS##asv.z + adv.z; lg_ = (lg_ > 0.f) ? lg_ : 0.2f * lg_;    \
    av_.z = msk_ * __expf(lg_);                                             \
    lg_ = lp3 + AS##asv.w + adv.w; lg_ = (lg_ > 0.f) ? lg_ : 0.2f * lg_;    \
    av_.w = msk_ * __expf(lg_);                                             \
    if (jc == 0) s_att[wvb][pj] = av_;                                      \
    ssa.x = fmaf(av_.x, jc0f, ssa.x); ssa.y = fmaf(av_.y, jc0f, ssa.y);     \
    ssa.z = fmaf(av_.z, jc0f, ssa.z); ssa.w = fmaf(av_.w, jc0f, ssa.w);     \
    _Pragma("unroll")                                                       \
    for (int p = 0; p < 8; p++) {                                           \
      float4 ap = s_att[wvb][p];                                            \
      float xf = ubf((unsigned)X[p]);                                       \
      ax0 = fmaf(ap.x, xf, ax0); ax1 = fmaf(ap.y, xf, ax1);                 \
      ax2 = fmaf(ap.z, xf, ax2); ax3 = fmaf(ap.w, xf, ax3);                 \
      ae0 = fmaf(hi ? ap.z : ap.x, E4[p], ae0);                             \
      ae1 = fmaf(hi ? ap.w : ap.y, E4[p], ae1);                             \
    }                                                                       \
  } while (0)

  int v = wv;
  int start = 0, dg = 0;
  float4 adv = make_float4(0.f, 0.f, 0.f, 0.f);
  if (v < N) { start = offsets[v]; dg = deg[v]; adv = A_d[v]; }

  while (v < N) {
    // prefetch next node's meta early (independent loads, clamped)
    const int v_next = v + nw;
    const int vc = min(v_next, N - 1);
    const int start_n = offsets[vc];
    const int dg_n = deg[vc];
    const float4 adv_n = A_d[vc];

    float ax0 = 0, ax1 = 0, ax2 = 0, ax3 = 0, ae0 = 0, ae1 = 0;
    float4 ssa = make_float4(0.f, 0.f, 0.f, 0.f);

    if (dg > 0) {
      const int ng = (dg + 7) >> 3;
      {
        int2 q_ = csr2[start + min(l32, dg - 1)];
        if (lane < 32) s_ids[wvb][l32] = q_;
      }
      ISSUE_G(axv, aev, a, 0);
      int g = 0;
      while (true) {
        if (g + 1 < ng) { REFILL(g + 1); ISSUE_G(bxv, bev, b, g + 1); }
        COMPUTE_G(axv, aev, a, g);
        if (++g >= ng) break;
        if (g + 1 < ng) { REFILL(g + 1); ISSUE_G(axv, aev, a, g + 1); }
        COMPUTE_G(bxv, bev, b, g);
        if (++g >= ng) break;
      }
    }

    // per-node epilogue: reduce denom, write agg (bf16) + denom
    #pragma unroll
    for (int m = 1; m <= 32; m <<= 1) {
      ssa.x += __shfl_xor(ssa.x, m, 64);
      ssa.y += __shfl_xor(ssa.y, m, 64);
      ssa.z += __shfl_xor(ssa.z, m, 64);
      ssa.w += __shfl_xor(ssa.w, m, 64);
    }
    const int base = v * 384;
    agg[base + lane]       = fbf(ax0);
    agg[base + 96 + lane]  = fbf(ax1);
    agg[base + 192 + lane] = fbf(ax2);
    agg[base + 288 + lane] = fbf(ax3);
    const int hA = hi ? 2 : 0;
    agg[base + hA * 96 + 64 + l32]       = fbf(ae0);
    agg[base + (hA + 1) * 96 + 64 + l32] = fbf(ae1);
    if (lane == 0) ((float4*)denom)[v] = ssa;

    v = v_next; start = start_n; dg = dg_n; adv = adv_n;
  }
#undef REFILL
#undef ISSUE_G
#undef COMPUTE_G
}

// ---------------- out = blockdiag(W_msg) * agg, /denom, +bias, LN ----------------
__launch_bounds__(128)
__global__ void k_out(const unsigned short* __restrict__ agg, const float* __restrict__ W_msg,
                      const float* __restrict__ denom, const float* __restrict__ bias,
                      const float* __restrict__ gamma, const float* __restrict__ beta,
                      float* __restrict__ out, int N, int T) {
  __shared__ float s_den[64];
  __shared__ float s_sum[2][16], s_sq[2][16];
  const int f = threadIdx.x;
  const int w = f >> 6;            // wave: heads 2w, 2w+1 -> cols 64w..64w+63
  const int l = f & 63;
  const int c16 = l & 15;
  const int rg = l >> 4;

  short8 wb[2][2][3];
  float biasv[2][2], gv[2][2], bv[2][2];
  #pragma unroll
  for (int hh = 0; hh < 2; hh++) {
    const int head = 2 * w + hh;
    #pragma unroll
    for (int ct = 0; ct < 2; ct++) {
      const int q = head * 32 + ct * 16 + c16;
      biasv[hh][ct] = bias[q]; gv[hh][ct] = gamma[q]; bv[hh][ct] = beta[q];
      #pragma unroll
      for (int kk = 0; kk < 3; kk++) {
        const float* p = &W_msg[q * 96 + kk * 32 + rg * 8];
        short8 s;
        #pragma unroll
        for (int i = 0; i < 8; i++) s[i] = (short)fbf(p[i]);
        wb[hh][ct][kk] = s;
      }
    }
  }

  for (int t = blockIdx.x; t < T; t += gridDim.x) {
    const int n0 = t * 16;
    if (f < 64) s_den[f] = denom[min(n0 + (f >> 2), N - 1) * 4 + (f & 3)];
    __syncthreads();

    f32x4 c[2][2] = {{{0.f,0.f,0.f,0.f},{0.f,0.f,0.f,0.f}},
                     {{0.f,0.f,0.f,0.f},{0.f,0.f,0.f,0.f}}};
    const int nA = min(n0 + c16, N - 1);
    #pragma unroll
    for (int hh = 0; hh < 2; hh++) {
      const int head = 2 * w + hh;
      #pragma unroll
      for (int kk = 0; kk < 3; kk++) {
        short8 a = *(const short8*)&agg[nA * 384 + head * 96 + kk * 32 + rg * 8];
        c[hh][0] = __builtin_amdgcn_mfma_f32_16x16x32_bf16(a, wb[hh][0][kk], c[hh][0], 0, 0, 0);
        c[hh][1] = __builtin_amdgcn_mfma_f32_16x16x32_bf16(a, wb[hh][1][kk], c[hh][1], 0, 0, 0);
      }
    }

    float val[2][2][4];
    #pragma unroll
    for (int hh = 0; hh < 2; hh++)
      #pragma unroll
      for (int ct = 0; ct < 2; ct++)
        #pragma unroll
        for (int r = 0; r < 4; r++) {
          const float d = s_den[(rg * 4 + r) * 4 + (2 * w + hh)] + 1e-9f;
          val[hh][ct][r] = c[hh][ct][r] / d + biasv[hh][ct];
        }

    float sr[4], qr[4];
    #pragma unroll
    for (int r = 0; r < 4; r++) {
      float s = 0.f, q2 = 0.f;
      #pragma unroll
      for (int hh = 0; hh < 2; hh++)
        #pragma unroll
        for (int ct = 0; ct < 2; ct++) { s += val[hh][ct][r]; q2 = fmaf(val[hh][ct][r], val[hh][ct][r], q2); }
      #pragma unroll
      for (int m = 1; m <= 8; m <<= 1) { s += __shfl_xor(s, m, 64); q2 += __shfl_xor(q2, m, 64); }
      sr[r] = s; qr[r] = q2;
    }
    if (c16 == 0) {
      #pragma unroll
      for (int r = 0; r < 4; r++) { s_sum[w][rg * 4 + r] = sr[r]; s_sq[w][rg * 4 + r] = qr[r]; }
    }
    __syncthreads();

    float mean[4], rstd[4];
    #pragma unroll
    for (int r = 0; r < 4; r++) {
      const int ni = rg * 4 + r;
      mean[r] = (s_sum[0][ni] + s_sum[1][ni]) * (1.f / 128.f);
      const float m2 = (s_sq[0][ni] + s_sq[1][ni]) * (1.f / 128.f);
      rstd[r] = rsqrtf(m2 - mean[r] * mean[r] + 1e-5f);
    }
    #pragma unroll
    for (int hh = 0; hh < 2; hh++)
      #pragma unroll
      for (int ct = 0; ct < 2; ct++)
        #pragma unroll
        for (int r = 0; r < 4; r++) {
          const int n = n0 + rg * 4 + r;
          if (n < N)
            out[n * 128 + (2 * w + hh) * 32 + ct * 16 + c16] =
                (val[hh][ct][r] - mean[r]) * rstd[r] * gv[hh][ct] + bv[hh][ct];
        }
    __syncthreads();
  }
}

extern "C" void kernel_launch(void* const* d_in, const int* in_sizes, int n_in,
                              void* d_out, int out_size, void* d_ws, size_t ws_size,
                              hipStream_t stream) {
  const float* x     = (const float*)d_in[0];
  const int*   ei    = (const int*)d_in[1];
  const float* ea    = (const float*)d_in[2];
  const float* W_msg = (const float*)d_in[3];
  const float* W_att = (const float*)d_in[4];
  const float* bias  = (const float*)d_in[5];
  const float* gamma = (const float*)d_in[6];
  const float* beta  = (const float*)d_in[7];
  float* out = (float*)d_out;

  const int N = in_sizes[0] / 64;
  const int E = in_sizes[1] / 2;
  const int* esrc = ei;
  const int* edst = ei + E;

  char* p = (char*)d_ws;
  int* deg      = (int*)p;            p += (size_t)N * 4;
  int* offsets  = (int*)p;            p += (size_t)N * 4;
  int* cursor   = (int*)p;            p += (size_t)N * 4;
  int* bsum     = (int*)p;            p += 2048 * 4;
  int2* csr2    = (int2*)p;           p += (size_t)E * 8;
  float4* A_s   = (float4*)p;         p += (size_t)N * 16;
  float4* A_d   = (float4*)p;         p += (size_t)N * 16;
  unsigned short* xb = (unsigned short*)p; p += (size_t)N * 64 * 2;
  unsigned short* agg = (unsigned short*)p; p += (size_t)N * 384 * 2;
  float* denom  = (float*)p;

  hipMemsetAsync(deg, 0, (size_t)N * sizeof(int), stream);
  const int SB = (N + 1023) / 1024;
  const int T = (N + 15) / 16;

  k_count<<<2048, 256, 0, stream>>>(edst, E, deg);
  k_scan1<<<SB, 1024, 0, stream>>>(deg, N, offsets, bsum);
  k_scan2<<<SB, 1024, 0, stream>>>(offsets, bsum, N, cursor);
  k_fill<<<2048, 256, 0, stream>>>(esrc, edst, E, cursor, csr2);
  k_prep<<<(N + 255) / 256, 256, 0, stream>>>(x, W_att, A_s, A_d, (unsigned*)xb, N);
  k_agg<<<2048, 256, 0, stream>>>(xb, ea, A_s, A_d, csr2, offsets, deg, W_att,
                                  agg, denom, N);
  k_out<<<2048, 128, 0, stream>>>(agg, W_msg, denom, bias, gamma, beta, out, N, T);
}